// Round 1
// baseline (2374.840 us; speedup 1.0000x reference)
//
#include <hip/hip_runtime.h>

#define N_NODES 100000
#define N_EDGES 1200000
#define N_GRAPHS 256
#define IN_C 5
#define HID_C 64
#define OUT_C 2

// deg accumulation: deg[v] = number of edges with dst==v (self-loop +1 added later)
__global__ void k_deg(const int* __restrict__ dst, float* __restrict__ deg) {
    int e = blockIdx.x * blockDim.x + threadIdx.x;
    if (e < N_EDGES) atomicAdd(&deg[dst[e]], 1.0f);
}

// dinv[v] = rsqrt(deg[v] + 1)  (self loop; always > 0)
__global__ void k_dinv(float* __restrict__ deg) {
    int v = blockIdx.x * blockDim.x + threadIdx.x;
    if (v < N_NODES) deg[v] = rsqrtf(deg[v] + 1.0f);
}

// g = (x @ W1) * dinv[n];  also acc = g (self-loop message init)
__global__ void k_g1(const float* __restrict__ x, const float* __restrict__ W,
                     const float* __restrict__ dinv,
                     float* __restrict__ g, float* __restrict__ acc) {
    __shared__ float sW[IN_C * HID_C];
    int tid = threadIdx.x;
    for (int i = tid; i < IN_C * HID_C; i += blockDim.x) sW[i] = W[i];
    __syncthreads();
    int idx = blockIdx.x * blockDim.x + tid;  // node*64 + c
    int n = idx >> 6, c = idx & 63;
    if (n >= N_NODES) return;
    float s = 0.f;
#pragma unroll
    for (int k = 0; k < IN_C; ++k) s += x[n * IN_C + k] * sW[k * HID_C + c];
    s *= dinv[n];
    g[idx] = s;
    acc[idx] = s;
}

// In-place: h (h1) -> g2 = (h @ W2) * dinv; also acc = g2.
// Block = 256 threads = 4 nodes x 64 channels. Rows staged in LDS so the
// in-place overwrite of h is safe (only this block touches these rows).
__global__ void k_g2(float* __restrict__ h, const float* __restrict__ W,
                     const float* __restrict__ dinv, float* __restrict__ acc) {
    __shared__ float sW[HID_C * HID_C];   // 16 KB
    __shared__ float sh[4][HID_C];
    int tid = threadIdx.x;
    for (int i = tid; i < HID_C * HID_C; i += 256) sW[i] = W[i];
    int n0 = blockIdx.x * 4;
    int ln = tid >> 6, c = tid & 63;
    sh[ln][c] = h[(n0 + ln) * HID_C + c];
    __syncthreads();
    float s = 0.f;
#pragma unroll
    for (int k = 0; k < HID_C; ++k) s += sh[ln][k] * sW[k * HID_C + c];
    s *= dinv[n0 + ln];
    h[(n0 + ln) * HID_C + c] = s;
    acc[(n0 + ln) * HID_C + c] = s;
}

// Edge scatter: acc[dst] += g[src], 16 lanes/edge x float4 (coalesced 256B rows)
__global__ void k_scatter(const int* __restrict__ src, const int* __restrict__ dst,
                          const float* __restrict__ g, float* __restrict__ acc) {
    int t = blockIdx.x * blockDim.x + threadIdx.x;
    int e = t >> 4;
    if (e >= N_EDGES) return;
    int q = (t & 15) << 2;  // channel offset 0,4,...,60
    int u = src[e], v = dst[e];
    const float4 val = *(const float4*)(g + (long)u * HID_C + q);
    float* a = acc + (long)v * HID_C + q;
    atomicAdd(a + 0, val.x);
    atomicAdd(a + 1, val.y);
    atomicAdd(a + 2, val.z);
    atomicAdd(a + 3, val.w);
}

// h_out = relu(acc * dinv[n] + b[c])
__global__ void k_finalize(const float* __restrict__ acc, const float* __restrict__ dinv,
                           const float* __restrict__ b, float* __restrict__ hout) {
    int idx = blockIdx.x * blockDim.x + threadIdx.x;
    if (idx >= N_NODES * HID_C) return;
    int n = idx >> 6, c = idx & 63;
    float v = acc[idx] * dinv[n] + b[c];
    hout[idx] = v > 0.f ? v : 0.f;
}

// One block (64 threads) per graph: binary-search sorted batch for the node
// range, mean-pool channel c per lane, then 64-lane shuffle-reduce FC -> out[g][2]
__global__ void k_pool(const float* __restrict__ h, const int* __restrict__ batch,
                       const float* __restrict__ Wfc, const float* __restrict__ bfc,
                       float* __restrict__ out) {
    int g = blockIdx.x;
    int c = threadIdx.x;  // 0..63
    int lo = 0, hi = N_NODES;
    while (lo < hi) { int mid = (lo + hi) >> 1; if (batch[mid] < g) lo = mid + 1; else hi = mid; }
    int start = lo;
    hi = N_NODES;
    while (lo < hi) { int mid = (lo + hi) >> 1; if (batch[mid] < g + 1) lo = mid + 1; else hi = mid; }
    int end = lo;
    float s = 0.f;
    for (int v = start; v < end; ++v) s += h[(long)v * HID_C + c];
    int cnt = end - start;
    float pooled = s / (float)(cnt > 0 ? cnt : 1);
    float o0 = pooled * Wfc[c * OUT_C + 0];
    float o1 = pooled * Wfc[c * OUT_C + 1];
#pragma unroll
    for (int off = 32; off > 0; off >>= 1) {
        o0 += __shfl_down(o0, off);
        o1 += __shfl_down(o1, off);
    }
    if (c == 0) {
        out[g * OUT_C + 0] = o0 + bfc[0];
        out[g * OUT_C + 1] = o1 + bfc[1];
    }
}

extern "C" void kernel_launch(void* const* d_in, const int* in_sizes, int n_in,
                              void* d_out, int out_size, void* d_ws, size_t ws_size,
                              hipStream_t stream) {
    const float* x    = (const float*)d_in[0];
    const int*   ei   = (const int*)d_in[1];
    const int*   src  = ei;             // edge_index[0]
    const int*   dst  = ei + N_EDGES;   // edge_index[1]
    const int*   batch= (const int*)d_in[2];
    const float* W1   = (const float*)d_in[3];
    const float* b1   = (const float*)d_in[4];
    const float* W2   = (const float*)d_in[5];
    const float* b2   = (const float*)d_in[6];
    const float* Wfc  = (const float*)d_in[7];
    const float* bfc  = (const float*)d_in[8];
    float* out = (float*)d_out;

    float* ws   = (float*)d_ws;
    float* dinv = ws;                       // N floats (deg temp -> dinv)
    float* buf0 = ws + 100352;              // N*64: g1 -> h1 -> g2 -> h2
    float* buf1 = buf0 + N_NODES * HID_C;   // N*64: acc1 -> acc2

    hipMemsetAsync(dinv, 0, N_NODES * sizeof(float), stream);
    k_deg<<<(N_EDGES + 255) / 256, 256, 0, stream>>>(dst, dinv);
    k_dinv<<<(N_NODES + 255) / 256, 256, 0, stream>>>(dinv);

    // Layer 1
    k_g1<<<(N_NODES * HID_C) / 256, 256, 0, stream>>>(x, W1, dinv, buf0, buf1);
    k_scatter<<<(N_EDGES * 16) / 256, 256, 0, stream>>>(src, dst, buf0, buf1);
    k_finalize<<<(N_NODES * HID_C) / 256, 256, 0, stream>>>(buf1, dinv, b1, buf0);

    // Layer 2 (g2 computed in-place over h1 in buf0; acc2 in buf1)
    k_g2<<<N_NODES / 4, 256, 0, stream>>>(buf0, W2, dinv, buf1);
    k_scatter<<<(N_EDGES * 16) / 256, 256, 0, stream>>>(src, dst, buf0, buf1);
    k_finalize<<<(N_NODES * HID_C) / 256, 256, 0, stream>>>(buf1, dinv, b2, buf0);

    // Pool + FC
    k_pool<<<N_GRAPHS, 64, 0, stream>>>(buf0, batch, Wfc, bfc, out);
}

// Round 2
// 550.261 us; speedup vs baseline: 4.3158x; 4.3158x over previous
//
#include <hip/hip_runtime.h>

#define N_NODES 100000
#define N_EDGES 1200000
#define N_GRAPHS 256
#define IN_C 5
#define HID_C 64
#define OUT_C 2
#define SCAN_BLK 1024
#define SCAN_NBLK ((N_NODES + SCAN_BLK - 1) / SCAN_BLK)   // 98

// in-degree histogram by dst (int atomics)
__global__ void k_hist(const int* __restrict__ dst, int* __restrict__ cnt) {
    int e = blockIdx.x * blockDim.x + threadIdx.x;
    if (e < N_EDGES) atomicAdd(&cnt[dst[e]], 1);
}

// dinv[v] = rsqrt(indeg[v] + 1)  (self loop)
__global__ void k_dinv(const int* __restrict__ cnt, float* __restrict__ dinv) {
    int v = blockIdx.x * blockDim.x + threadIdx.x;
    if (v < N_NODES) dinv[v] = rsqrtf((float)cnt[v] + 1.0f);
}

// exclusive scan, stage 1: per-block Hillis-Steele, write block totals
__global__ void k_scan1(const int* __restrict__ cnt, int* __restrict__ rs,
                        int* __restrict__ part) {
    __shared__ int tmp[SCAN_BLK];
    int t = threadIdx.x;
    int i = blockIdx.x * SCAN_BLK + t;
    int v = (i < N_NODES) ? cnt[i] : 0;
    tmp[t] = v;
    __syncthreads();
    for (int off = 1; off < SCAN_BLK; off <<= 1) {
        int add = (t >= off) ? tmp[t - off] : 0;
        __syncthreads();
        tmp[t] += add;
        __syncthreads();
    }
    if (i < N_NODES) rs[i] = tmp[t] - v;            // exclusive within block
    if (t == SCAN_BLK - 1) part[blockIdx.x] = tmp[t];
}

// stage 2: serial exclusive scan of 98 partials (trivial)
__global__ void k_scan2(int* __restrict__ part) {
    if (threadIdx.x == 0) {
        int acc = 0;
        for (int i = 0; i < SCAN_NBLK; ++i) { int p = part[i]; part[i] = acc; acc += p; }
    }
}

// stage 3: add block offsets -> rs = global exclusive scan (row_start)
__global__ void k_scan3(int* __restrict__ rs, const int* __restrict__ part) {
    int i = blockIdx.x * SCAN_BLK + threadIdx.x;
    if (i < N_NODES) rs[i] += part[blockIdx.x];
}

// fill CSR: pos = rs[dst]++ (rs becomes row_end after this kernel)
__global__ void k_fill(const int* __restrict__ src, const int* __restrict__ dst,
                       int* __restrict__ rs, int* __restrict__ csr_src) {
    int e = blockIdx.x * blockDim.x + threadIdx.x;
    if (e < N_EDGES) {
        int pos = atomicAdd(&rs[dst[e]], 1);
        csr_src[pos] = src[e];
    }
}

// g = (x @ W1) * dinv[n]
__global__ void k_g1(const float* __restrict__ x, const float* __restrict__ W,
                     const float* __restrict__ dinv, float* __restrict__ g) {
    __shared__ float sW[IN_C * HID_C];
    int tid = threadIdx.x;
    for (int i = tid; i < IN_C * HID_C; i += blockDim.x) sW[i] = W[i];
    __syncthreads();
    int idx = blockIdx.x * blockDim.x + tid;  // node*64 + c
    int n = idx >> 6, c = idx & 63;
    if (n >= N_NODES) return;
    float s = 0.f;
#pragma unroll
    for (int k = 0; k < IN_C; ++k) s += x[n * IN_C + k] * sW[k * HID_C + c];
    g[idx] = s * dinv[n];
}

// g2 = (h @ W2) * dinv ; block = 4 nodes x 64 channels, W + h rows in LDS
__global__ void k_g2(const float* __restrict__ h, const float* __restrict__ W,
                     const float* __restrict__ dinv, float* __restrict__ g) {
    __shared__ float sW[HID_C * HID_C];   // 16 KB
    __shared__ float sh[4][HID_C];
    int tid = threadIdx.x;
    for (int i = tid; i < HID_C * HID_C; i += 256) sW[i] = W[i];
    int n0 = blockIdx.x * 4;
    int ln = tid >> 6, c = tid & 63;
    sh[ln][c] = h[(n0 + ln) * HID_C + c];
    __syncthreads();
    float s = 0.f;
#pragma unroll
    for (int k = 0; k < HID_C; ++k) s += sh[ln][k] * sW[k * HID_C + c];
    g[(n0 + ln) * HID_C + c] = s * dinv[n0 + ln];
}

// gather: one wave per node; lane = channel. h[v] = relu((g[v] + sum g[u]) * dinv[v] + b)
__global__ void k_gather(const float* __restrict__ g, const int* __restrict__ csr_src,
                         const int* __restrict__ row_end, const int* __restrict__ cnt,
                         const float* __restrict__ dinv, const float* __restrict__ b,
                         float* __restrict__ hout) {
    int v = blockIdx.x * (blockDim.x >> 6) + (threadIdx.x >> 6);
    int c = threadIdx.x & 63;
    if (v >= N_NODES) return;
    int end = row_end[v];
    int n = cnt[v];
    int k = end - n;
    float s = g[(long)v * HID_C + c];   // self-loop message
    // unroll-by-2 for memory-level parallelism
    for (; k + 1 < end; k += 2) {
        int u0 = csr_src[k], u1 = csr_src[k + 1];
        s += g[(long)u0 * HID_C + c];
        s += g[(long)u1 * HID_C + c];
    }
    if (k < end) s += g[(long)csr_src[k] * HID_C + c];
    float o = s * dinv[v] + b[c];
    hout[(long)v * HID_C + c] = fmaxf(o, 0.f);
}

// one block (64 threads) per graph: binary-search node range, mean-pool, FC
__global__ void k_pool(const float* __restrict__ h, const int* __restrict__ batch,
                       const float* __restrict__ Wfc, const float* __restrict__ bfc,
                       float* __restrict__ out) {
    int g = blockIdx.x;
    int c = threadIdx.x;  // 0..63
    int lo = 0, hi = N_NODES;
    while (lo < hi) { int mid = (lo + hi) >> 1; if (batch[mid] < g) lo = mid + 1; else hi = mid; }
    int start = lo;
    hi = N_NODES;
    while (lo < hi) { int mid = (lo + hi) >> 1; if (batch[mid] < g + 1) lo = mid + 1; else hi = mid; }
    int end = lo;
    float s = 0.f;
    for (int v = start; v < end; ++v) s += h[(long)v * HID_C + c];
    int cnt = end - start;
    float pooled = s / (float)(cnt > 0 ? cnt : 1);
    float o0 = pooled * Wfc[c * OUT_C + 0];
    float o1 = pooled * Wfc[c * OUT_C + 1];
#pragma unroll
    for (int off = 32; off > 0; off >>= 1) {
        o0 += __shfl_down(o0, off);
        o1 += __shfl_down(o1, off);
    }
    if (c == 0) {
        out[g * OUT_C + 0] = o0 + bfc[0];
        out[g * OUT_C + 1] = o1 + bfc[1];
    }
}

extern "C" void kernel_launch(void* const* d_in, const int* in_sizes, int n_in,
                              void* d_out, int out_size, void* d_ws, size_t ws_size,
                              hipStream_t stream) {
    const float* x    = (const float*)d_in[0];
    const int*   ei   = (const int*)d_in[1];
    const int*   src  = ei;             // edge_index[0]
    const int*   dst  = ei + N_EDGES;   // edge_index[1]
    const int*   batch= (const int*)d_in[2];
    const float* W1   = (const float*)d_in[3];
    const float* b1   = (const float*)d_in[4];
    const float* W2   = (const float*)d_in[5];
    const float* b2   = (const float*)d_in[6];
    const float* Wfc  = (const float*)d_in[7];
    const float* bfc  = (const float*)d_in[8];
    float* out = (float*)d_out;

    // workspace layout (all offsets in 4B elems, padded)
    float* ws   = (float*)d_ws;
    float* dinv = ws;                        // 100352
    int*   cnt  = (int*)(ws + 100352);       // 100352
    int*   rs   = cnt + 100352;              // 100352  (row_start -> row_end)
    int*   part = rs + 100352;               // 1024
    int*   csr  = part + 1024;               // 1200128 (src node per incoming edge)
    float* buf0 = (float*)(csr + 1200128);   // N*64: g1 / g2
    float* buf1 = buf0 + N_NODES * HID_C;    // N*64: h1 / h2

    // ---- build degrees + CSR (per launch; ws is re-poisoned) ----
    hipMemsetAsync(cnt, 0, N_NODES * sizeof(int), stream);
    k_hist<<<(N_EDGES + 255) / 256, 256, 0, stream>>>(dst, cnt);
    k_dinv<<<(N_NODES + 255) / 256, 256, 0, stream>>>(cnt, dinv);
    k_scan1<<<SCAN_NBLK, SCAN_BLK, 0, stream>>>(cnt, rs, part);
    k_scan2<<<1, 64, 0, stream>>>(part);
    k_scan3<<<SCAN_NBLK, SCAN_BLK, 0, stream>>>(rs, part);
    k_fill<<<(N_EDGES + 255) / 256, 256, 0, stream>>>(src, dst, rs, csr);

    // ---- layer 1 ----
    k_g1<<<(N_NODES * HID_C) / 256, 256, 0, stream>>>(x, W1, dinv, buf0);
    k_gather<<<(N_NODES + 3) / 4, 256, 0, stream>>>(buf0, csr, rs, cnt, dinv, b1, buf1);

    // ---- layer 2 ----
    k_g2<<<N_NODES / 4, 256, 0, stream>>>(buf1, W2, dinv, buf0);
    k_gather<<<(N_NODES + 3) / 4, 256, 0, stream>>>(buf0, csr, rs, cnt, dinv, b2, buf1);

    // ---- pool + FC ----
    k_pool<<<N_GRAPHS, 64, 0, stream>>>(buf1, batch, Wfc, bfc, out);
}

// Round 3
// 426.323 us; speedup vs baseline: 5.5705x; 1.2907x over previous
//
#include <hip/hip_runtime.h>

#define N_NODES 100000
#define N_EDGES 1200000
#define N_GRAPHS 256
#define IN_C 5
#define HID_C 64
#define OUT_C 2
#define SCAN_BLK 1024
#define SCAN_NBLK ((N_NODES + SCAN_BLK - 1) / SCAN_BLK)   // 98
#define POOL_NPW 16   // nodes per wave in pool stage 1

// in-degree histogram by dst (int atomics)
__global__ void k_hist(const int* __restrict__ dst, int* __restrict__ cnt) {
    int e = blockIdx.x * blockDim.x + threadIdx.x;
    if (e < N_EDGES) atomicAdd(&cnt[dst[e]], 1);
}

// dinv[v] = rsqrt(indeg[v] + 1)  (self loop)
__global__ void k_dinv(const int* __restrict__ cnt, float* __restrict__ dinv) {
    int v = blockIdx.x * blockDim.x + threadIdx.x;
    if (v < N_NODES) dinv[v] = rsqrtf((float)cnt[v] + 1.0f);
}

// exclusive scan, stage 1: per-block Hillis-Steele, write block totals
__global__ void k_scan1(const int* __restrict__ cnt, int* __restrict__ rs,
                        int* __restrict__ part) {
    __shared__ int tmp[SCAN_BLK];
    int t = threadIdx.x;
    int i = blockIdx.x * SCAN_BLK + t;
    int v = (i < N_NODES) ? cnt[i] : 0;
    tmp[t] = v;
    __syncthreads();
    for (int off = 1; off < SCAN_BLK; off <<= 1) {
        int add = (t >= off) ? tmp[t - off] : 0;
        __syncthreads();
        tmp[t] += add;
        __syncthreads();
    }
    if (i < N_NODES) rs[i] = tmp[t] - v;            // exclusive within block
    if (t == SCAN_BLK - 1) part[blockIdx.x] = tmp[t];
}

// stage 2: serial exclusive scan of 98 partials (trivial)
__global__ void k_scan2(int* __restrict__ part) {
    if (threadIdx.x == 0) {
        int acc = 0;
        for (int i = 0; i < SCAN_NBLK; ++i) { int p = part[i]; part[i] = acc; acc += p; }
    }
}

// stage 3: add block offsets -> rs = global exclusive scan (row_start)
__global__ void k_scan3(int* __restrict__ rs, const int* __restrict__ part) {
    int i = blockIdx.x * SCAN_BLK + threadIdx.x;
    if (i < N_NODES) rs[i] += part[blockIdx.x];
}

// fill CSR: pos = rs[dst]++ (rs becomes row_end after this kernel)
__global__ void k_fill(const int* __restrict__ src, const int* __restrict__ dst,
                       int* __restrict__ rs, int* __restrict__ csr_src) {
    int e = blockIdx.x * blockDim.x + threadIdx.x;
    if (e < N_EDGES) {
        int pos = atomicAdd(&rs[dst[e]], 1);
        csr_src[pos] = src[e];
    }
}

// g = (x @ W1) * dinv[n]
__global__ void k_g1(const float* __restrict__ x, const float* __restrict__ W,
                     const float* __restrict__ dinv, float* __restrict__ g) {
    __shared__ float sW[IN_C * HID_C];
    int tid = threadIdx.x;
    for (int i = tid; i < IN_C * HID_C; i += blockDim.x) sW[i] = W[i];
    __syncthreads();
    int idx = blockIdx.x * blockDim.x + tid;  // node*64 + c
    int n = idx >> 6, c = idx & 63;
    if (n >= N_NODES) return;
    float s = 0.f;
#pragma unroll
    for (int k = 0; k < IN_C; ++k) s += x[n * IN_C + k] * sW[k * HID_C + c];
    g[idx] = s * dinv[n];
}

// g2 = (h @ W2) * dinv ; block = 256 thr = 4 waves, 16 nodes/block (4/wave)
// to amortize the 16KB W2 LDS stage over more rows
__global__ void k_g2(const float* __restrict__ h, const float* __restrict__ W,
                     const float* __restrict__ dinv, float* __restrict__ g) {
    __shared__ float sW[HID_C * HID_C];   // 16 KB
    __shared__ float sh[16][HID_C];       // 4 KB
    int tid = threadIdx.x;
    for (int i = tid; i < HID_C * HID_C; i += 256) sW[i] = W[i];
    int n0 = blockIdx.x * 16;
    int w = tid >> 6, c = tid & 63;
#pragma unroll
    for (int j = 0; j < 4; ++j) {
        int ln = w * 4 + j;
        sh[ln][c] = h[(long)(n0 + ln) * HID_C + c];
    }
    __syncthreads();
#pragma unroll
    for (int j = 0; j < 4; ++j) {
        int ln = w * 4 + j;
        float s = 0.f;
#pragma unroll
        for (int k = 0; k < HID_C; ++k) s += sh[ln][k] * sW[k * HID_C + c];
        g[(long)(n0 + ln) * HID_C + c] = s * dinv[n0 + ln];
    }
}

// gather: one wave per node; lane = channel. h[v] = relu((g[v] + sum g[u]) * dinv[v] + b)
__global__ void k_gather(const float* __restrict__ g, const int* __restrict__ csr_src,
                         const int* __restrict__ row_end, const int* __restrict__ cnt,
                         const float* __restrict__ dinv, const float* __restrict__ b,
                         float* __restrict__ hout) {
    int v = blockIdx.x * (blockDim.x >> 6) + (threadIdx.x >> 6);
    int c = threadIdx.x & 63;
    if (v >= N_NODES) return;
    int end = row_end[v];
    int n = cnt[v];
    int k = end - n;
    float s = g[(long)v * HID_C + c];   // self-loop message
    // unroll-by-4 for memory-level parallelism
    for (; k + 3 < end; k += 4) {
        int u0 = csr_src[k], u1 = csr_src[k + 1], u2 = csr_src[k + 2], u3 = csr_src[k + 3];
        float a0 = g[(long)u0 * HID_C + c];
        float a1 = g[(long)u1 * HID_C + c];
        float a2 = g[(long)u2 * HID_C + c];
        float a3 = g[(long)u3 * HID_C + c];
        s += (a0 + a1) + (a2 + a3);
    }
    for (; k < end; ++k) s += g[(long)csr_src[k] * HID_C + c];
    float o = s * dinv[v] + b[c];
    hout[(long)v * HID_C + c] = fmaxf(o, 0.f);
}

// pool stage 1: each wave scans POOL_NPW contiguous nodes; running per-graph sum,
// flush (atomicAdd) only at graph boundaries (batch sorted => ~1 flush/wave)
__global__ void k_pool1(const float* __restrict__ h, const int* __restrict__ batch,
                        float* __restrict__ pooled) {
    int wave = (blockIdx.x * blockDim.x + threadIdx.x) >> 6;
    int c = threadIdx.x & 63;
    int n0 = wave * POOL_NPW;
    if (n0 >= N_NODES) return;
    int n1 = n0 + POOL_NPW;
    if (n1 > N_NODES) n1 = N_NODES;
    int curg = batch[n0];
    float s = 0.f;
    for (int n = n0; n < n1; ++n) {
        int gg = batch[n];
        if (gg != curg) {
            atomicAdd(&pooled[curg * HID_C + c], s);
            s = 0.f;
            curg = gg;
        }
        s += h[(long)n * HID_C + c];
    }
    atomicAdd(&pooled[curg * HID_C + c], s);
}

// pool stage 2: mean + FC. One block (64 thr) per graph.
__global__ void k_fc(const float* __restrict__ pooled, const int* __restrict__ batch,
                     const float* __restrict__ Wfc, const float* __restrict__ bfc,
                     float* __restrict__ out) {
    int g = blockIdx.x;
    int c = threadIdx.x;  // 0..63
    int lo = 0, hi = N_NODES;
    while (lo < hi) { int mid = (lo + hi) >> 1; if (batch[mid] < g) lo = mid + 1; else hi = mid; }
    int start = lo;
    hi = N_NODES;
    while (lo < hi) { int mid = (lo + hi) >> 1; if (batch[mid] < g + 1) lo = mid + 1; else hi = mid; }
    int cnt = lo - start;
    float pv = pooled[g * HID_C + c] / (float)(cnt > 0 ? cnt : 1);
    float o0 = pv * Wfc[c * OUT_C + 0];
    float o1 = pv * Wfc[c * OUT_C + 1];
#pragma unroll
    for (int off = 32; off > 0; off >>= 1) {
        o0 += __shfl_down(o0, off);
        o1 += __shfl_down(o1, off);
    }
    if (c == 0) {
        out[g * OUT_C + 0] = o0 + bfc[0];
        out[g * OUT_C + 1] = o1 + bfc[1];
    }
}

extern "C" void kernel_launch(void* const* d_in, const int* in_sizes, int n_in,
                              void* d_out, int out_size, void* d_ws, size_t ws_size,
                              hipStream_t stream) {
    const float* x    = (const float*)d_in[0];
    const int*   ei   = (const int*)d_in[1];
    const int*   src  = ei;             // edge_index[0]
    const int*   dst  = ei + N_EDGES;   // edge_index[1]
    const int*   batch= (const int*)d_in[2];
    const float* W1   = (const float*)d_in[3];
    const float* b1   = (const float*)d_in[4];
    const float* W2   = (const float*)d_in[5];
    const float* b2   = (const float*)d_in[6];
    const float* Wfc  = (const float*)d_in[7];
    const float* bfc  = (const float*)d_in[8];
    float* out = (float*)d_out;

    // workspace layout (all offsets in 4B elems, padded)
    float* ws     = (float*)d_ws;
    float* dinv   = ws;                        // 100352
    int*   cnt    = (int*)(ws + 100352);       // 100352
    int*   rs     = cnt + 100352;              // 100352  (row_start -> row_end)
    int*   part   = rs + 100352;               // 1024
    int*   csr    = part + 1024;               // 1200128 (src node per incoming edge)
    float* buf0   = (float*)(csr + 1200128);   // N*64: g1 / g2
    float* buf1   = buf0 + N_NODES * HID_C;    // N*64: h1 / h2
    float* pooled = buf1 + N_NODES * HID_C;    // 256*64

    // ---- build degrees + CSR (per launch; ws is re-poisoned) ----
    hipMemsetAsync(cnt, 0, N_NODES * sizeof(int), stream);
    hipMemsetAsync(pooled, 0, N_GRAPHS * HID_C * sizeof(float), stream);
    k_hist<<<(N_EDGES + 255) / 256, 256, 0, stream>>>(dst, cnt);
    k_dinv<<<(N_NODES + 255) / 256, 256, 0, stream>>>(cnt, dinv);
    k_scan1<<<SCAN_NBLK, SCAN_BLK, 0, stream>>>(cnt, rs, part);
    k_scan2<<<1, 64, 0, stream>>>(part);
    k_scan3<<<SCAN_NBLK, SCAN_BLK, 0, stream>>>(rs, part);
    k_fill<<<(N_EDGES + 255) / 256, 256, 0, stream>>>(src, dst, rs, csr);

    // ---- layer 1 ----
    k_g1<<<(N_NODES * HID_C) / 256, 256, 0, stream>>>(x, W1, dinv, buf0);
    k_gather<<<(N_NODES + 3) / 4, 256, 0, stream>>>(buf0, csr, rs, cnt, dinv, b1, buf1);

    // ---- layer 2 ----
    k_g2<<<N_NODES / 16, 256, 0, stream>>>(buf1, W2, dinv, buf0);
    k_gather<<<(N_NODES + 3) / 4, 256, 0, stream>>>(buf0, csr, rs, cnt, dinv, b2, buf1);

    // ---- pool + FC ----
    {
        int waves = (N_NODES + POOL_NPW - 1) / POOL_NPW;       // 6250
        int blocks = (waves * 64 + 255) / 256;                 // 1563
        k_pool1<<<blocks, 256, 0, stream>>>(buf1, batch, pooled);
    }
    k_fc<<<N_GRAPHS, 64, 0, stream>>>(pooled, batch, Wfc, bfc, out);
}